// Round 1
// baseline (444.926 us; speedup 1.0000x reference)
//
#include <hip/hip_runtime.h>

#define IN_DIM 128
#define OUT_DIM 64

// ---------------------------------------------------------------------------
// Kernel 1: xw[n][c] = sum_k x[n][k] * W[k][c] + b[c]
// Block = 256 threads = 4 row-groups of 64 lanes; lane = output channel c.
// W (128x64 f32 = 32KB) staged in LDS once per block. x rows staged per iter.
// ---------------------------------------------------------------------------
__global__ __launch_bounds__(256) void gemm_xw_kernel(
    const float* __restrict__ x, const float* __restrict__ W,
    const float* __restrict__ b, float* __restrict__ xw, int n_nodes) {
    __shared__ float Ws[IN_DIM * OUT_DIM];   // 32 KB
    __shared__ float xs[4][IN_DIM];          // 2 KB

    const int tid  = threadIdx.x;
    const int lane = tid & 63;     // output channel
    const int rgrp = tid >> 6;     // 0..3 row within block-tile

    for (int i = tid; i < IN_DIM * OUT_DIM; i += 256) Ws[i] = W[i];
    const float bias = b[lane];

    for (int base = blockIdx.x * 4; base < n_nodes; base += gridDim.x * 4) {
        const int row = base + rgrp;
        __syncthreads();
        if (row < n_nodes) {
            xs[rgrp][lane]      = x[row * IN_DIM + lane];
            xs[rgrp][lane + 64] = x[row * IN_DIM + lane + 64];
        }
        __syncthreads();
        if (row < n_nodes) {
            float acc = bias;
            #pragma unroll
            for (int k = 0; k < IN_DIM; ++k)
                acc = fmaf(xs[rgrp][k], Ws[k * OUT_DIM + lane], acc);
            xw[row * OUT_DIM + lane] = acc;
        }
    }
}

// ---------------------------------------------------------------------------
// Kernel 2: per-edge scatter. One 64-lane wave per edge; lane = output dim.
// out[row[e]][lane] += val[e] * xw[col[e]][lane]   (atomic)
// ---------------------------------------------------------------------------
__global__ __launch_bounds__(256) void edge_scatter_kernel(
    const float* __restrict__ xw, const int* __restrict__ erow,
    const int* __restrict__ ecol, const float* __restrict__ eval_,
    float* __restrict__ out, int n_edges) {
    const int lane  = threadIdx.x & 63;
    const int wid   = (blockIdx.x * blockDim.x + threadIdx.x) >> 6;
    const int nwave = (gridDim.x * blockDim.x) >> 6;

    for (int e = wid; e < n_edges; e += nwave) {
        const int   r = erow[e];
        const int   c = ecol[e];
        const float v = eval_[e];
        const float m = v * xw[c * OUT_DIM + lane];
        atomicAdd(&out[r * OUT_DIM + lane], m);
    }
}

// ---------------------------------------------------------------------------
// Kernel 3: in-place ReLU, float4-vectorized (out_size divisible by 4).
// ---------------------------------------------------------------------------
__global__ __launch_bounds__(256) void relu_kernel(float4* __restrict__ p, int n4) {
    const int stride = gridDim.x * blockDim.x;
    for (int i = blockIdx.x * blockDim.x + threadIdx.x; i < n4; i += stride) {
        float4 v = p[i];
        v.x = fmaxf(v.x, 0.f);
        v.y = fmaxf(v.y, 0.f);
        v.z = fmaxf(v.z, 0.f);
        v.w = fmaxf(v.w, 0.f);
        p[i] = v;
    }
}

extern "C" void kernel_launch(void* const* d_in, const int* in_sizes, int n_in,
                              void* d_out, int out_size, void* d_ws, size_t ws_size,
                              hipStream_t stream) {
    const float* x     = (const float*)d_in[0];
    const int*   erow  = (const int*)d_in[1];
    const int*   ecol  = (const int*)d_in[2];
    const float* eval_ = (const float*)d_in[3];
    const float* W     = (const float*)d_in[4];
    const float* b     = (const float*)d_in[5];
    float*       out   = (float*)d_out;

    const int n_nodes = in_sizes[0] / IN_DIM;
    const int n_edges = in_sizes[1];

    float* xw = (float*)d_ws;  // n_nodes * OUT_DIM floats = 25.6 MB

    // zero accumulator (graph-capturable)
    hipMemsetAsync(d_out, 0, (size_t)out_size * sizeof(float), stream);

    // 1) xw = x @ W + b
    {
        int grid = (n_nodes + 3) / 4;
        gemm_xw_kernel<<<grid, 256, 0, stream>>>(x, W, b, xw, n_nodes);
    }
    // 2) edge scatter with atomics
    {
        int grid = 8192;  // 32768 waves, grid-stride over 1.6M edges
        edge_scatter_kernel<<<grid, 256, 0, stream>>>(xw, erow, ecol, eval_, out, n_edges);
    }
    // 3) ReLU in place
    {
        int n4 = out_size / 4;
        int grid = 2048;
        relu_kernel<<<grid, 256, 0, stream>>>((float4*)d_out, n4);
    }
}

// Round 2
// 360.773 us; speedup vs baseline: 1.2333x; 1.2333x over previous
//
#include <hip/hip_runtime.h>

#define IN_DIM 128
#define OUT_DIM 64
#define SCAN_CHUNK 2048   // elements per scan block (256 thr x 8)

// ---------------------------------------------------------------------------
// Kernel 1: xw[n][c] = sum_k x[n][k] * W[k][c] + b[c]
// Block = 256 threads = 4 row-groups of 64 lanes; lane = output channel c.
// ---------------------------------------------------------------------------
__global__ __launch_bounds__(256) void gemm_xw_kernel(
    const float* __restrict__ x, const float* __restrict__ W,
    const float* __restrict__ b, float* __restrict__ xw, int n_nodes) {
    __shared__ float Ws[IN_DIM * OUT_DIM];   // 32 KB
    __shared__ float xs[4][IN_DIM];          // 2 KB

    const int tid  = threadIdx.x;
    const int lane = tid & 63;     // output channel
    const int rgrp = tid >> 6;     // 0..3 row within block-tile

    for (int i = tid; i < IN_DIM * OUT_DIM; i += 256) Ws[i] = W[i];
    const float bias = b[lane];

    for (int base = blockIdx.x * 4; base < n_nodes; base += gridDim.x * 4) {
        const int row = base + rgrp;
        __syncthreads();
        if (row < n_nodes) {
            xs[rgrp][lane]      = x[row * IN_DIM + lane];
            xs[rgrp][lane + 64] = x[row * IN_DIM + lane + 64];
        }
        __syncthreads();
        if (row < n_nodes) {
            float acc = bias;
            #pragma unroll
            for (int k = 0; k < IN_DIM; ++k)
                acc = fmaf(xs[rgrp][k], Ws[k * OUT_DIM + lane], acc);
            xw[row * OUT_DIM + lane] = acc;
        }
    }
}

// ---------------------------------------------------------------------------
// Kernel 2: histogram of edge rows. hist must be pre-zeroed.
// ---------------------------------------------------------------------------
__global__ __launch_bounds__(256) void hist_kernel(
    const int* __restrict__ erow, int* __restrict__ hist, int n_edges) {
    int e = blockIdx.x * blockDim.x + threadIdx.x;
    if (e < n_edges) atomicAdd(&hist[erow[e]], 1);
}

// ---------------------------------------------------------------------------
// Kernel 3a: per-block exclusive scan. off[i] = exclusive prefix of hist
// WITHIN its 2048-chunk; bsum[blk] = chunk total.
// ---------------------------------------------------------------------------
__global__ __launch_bounds__(256) void scan_block_kernel(
    const int* __restrict__ hist, int* __restrict__ off,
    int* __restrict__ bsum, int n) {
    const int t = threadIdx.x;
    const int base = blockIdx.x * SCAN_CHUNK + t * 8;
    int v[8];
    #pragma unroll
    for (int j = 0; j < 8; ++j) v[j] = (base + j < n) ? hist[base + j] : 0;
    int s = 0;
    #pragma unroll
    for (int j = 0; j < 8; ++j) { int tv = v[j]; v[j] = s; s += tv; }
    // inclusive wave scan of per-thread totals
    int inc = s;
    #pragma unroll
    for (int d = 1; d < 64; d <<= 1) {
        int u = __shfl_up(inc, d, 64);
        if ((t & 63) >= d) inc += u;
    }
    __shared__ int wsum[4];
    if ((t & 63) == 63) wsum[t >> 6] = inc;
    __syncthreads();
    int wprefix = 0;
    #pragma unroll
    for (int w = 0; w < 4; ++w) if (w < (t >> 6)) wprefix += wsum[w];
    const int tprefix = wprefix + (inc - s);   // exclusive prefix of this thread
    #pragma unroll
    for (int j = 0; j < 8; ++j)
        if (base + j < n) off[base + j] = tprefix + v[j];
    if (t == 255) bsum[blockIdx.x] = wprefix + inc;  // block total
}

// ---------------------------------------------------------------------------
// Kernel 3b: single-block exclusive scan of block sums (nb <= 2048), in place.
// ---------------------------------------------------------------------------
__global__ __launch_bounds__(256) void scan_top_kernel(int* __restrict__ bsum, int nb) {
    const int t = threadIdx.x;
    const int base = t * 8;
    int v[8];
    #pragma unroll
    for (int j = 0; j < 8; ++j) v[j] = (base + j < nb) ? bsum[base + j] : 0;
    int s = 0;
    #pragma unroll
    for (int j = 0; j < 8; ++j) { int tv = v[j]; v[j] = s; s += tv; }
    int inc = s;
    #pragma unroll
    for (int d = 1; d < 64; d <<= 1) {
        int u = __shfl_up(inc, d, 64);
        if ((t & 63) >= d) inc += u;
    }
    __shared__ int wsum[4];
    if ((t & 63) == 63) wsum[t >> 6] = inc;
    __syncthreads();
    int wprefix = 0;
    #pragma unroll
    for (int w = 0; w < 4; ++w) if (w < (t >> 6)) wprefix += wsum[w];
    const int tprefix = wprefix + (inc - s);
    __syncthreads();
    #pragma unroll
    for (int j = 0; j < 8; ++j)
        if (base + j < nb) bsum[base + j] = tprefix + v[j];
}

// ---------------------------------------------------------------------------
// Kernel 4: reorder edges into row-sorted {col, val_bits} pairs.
// pos = bsum[r>>11] + atomicAdd(&off[r], 1). Afterwards off[r] (local) + bsum
// gives the END pointer of row r — used by the gather kernel.
// ---------------------------------------------------------------------------
__global__ __launch_bounds__(256) void reorder_kernel(
    const int* __restrict__ erow, const int* __restrict__ ecol,
    const float* __restrict__ eval_, int* __restrict__ off,
    const int* __restrict__ bsum, int2* __restrict__ ecs, int n_edges) {
    int e = blockIdx.x * blockDim.x + threadIdx.x;
    if (e >= n_edges) return;
    const int r = erow[e];
    const int pos = bsum[r >> 11] + atomicAdd(&off[r], 1);
    int2 p;
    p.x = ecol[e];
    p.y = __float_as_int(eval_[e]);
    ecs[pos] = p;
}

// ---------------------------------------------------------------------------
// Kernel 5: gather-aggregate + ReLU. One 64-lane wave per row; lane = dim.
// start/end derived from post-reorder off[] (end pointers) + bsum prefixes.
// ---------------------------------------------------------------------------
__global__ __launch_bounds__(256) void gather_relu_kernel(
    const float* __restrict__ xw, const int2* __restrict__ ecs,
    const int* __restrict__ off, const int* __restrict__ bsum,
    float* __restrict__ out, int n_nodes) {
    const int lane = threadIdx.x & 63;
    const int r = (blockIdx.x * blockDim.x + threadIdx.x) >> 6;
    if (r >= n_nodes) return;

    const int end   = bsum[r >> 11] + off[r];
    const int start = (r == 0) ? 0 : (bsum[(r - 1) >> 11] + off[r - 1]);

    float acc = 0.f;
    int j = start;
    for (; j + 4 <= end; j += 4) {
        const int2 e0 = ecs[j], e1 = ecs[j + 1], e2 = ecs[j + 2], e3 = ecs[j + 3];
        const float a0 = xw[(size_t)e0.x * OUT_DIM + lane];
        const float a1 = xw[(size_t)e1.x * OUT_DIM + lane];
        const float a2 = xw[(size_t)e2.x * OUT_DIM + lane];
        const float a3 = xw[(size_t)e3.x * OUT_DIM + lane];
        acc = fmaf(__int_as_float(e0.y), a0, acc);
        acc = fmaf(__int_as_float(e1.y), a1, acc);
        acc = fmaf(__int_as_float(e2.y), a2, acc);
        acc = fmaf(__int_as_float(e3.y), a3, acc);
    }
    for (; j < end; ++j) {
        const int2 e0 = ecs[j];
        acc = fmaf(__int_as_float(e0.y), xw[(size_t)e0.x * OUT_DIM + lane], acc);
    }
    out[(size_t)r * OUT_DIM + lane] = fmaxf(acc, 0.f);
}

// ---------------------------------------------------------------------------
// Fallback (ws too small): original atomic scatter path.
// ---------------------------------------------------------------------------
__global__ __launch_bounds__(256) void edge_scatter_kernel(
    const float* __restrict__ xw, const int* __restrict__ erow,
    const int* __restrict__ ecol, const float* __restrict__ eval_,
    float* __restrict__ out, int n_edges) {
    const int lane  = threadIdx.x & 63;
    const int wid   = (blockIdx.x * blockDim.x + threadIdx.x) >> 6;
    const int nwave = (gridDim.x * blockDim.x) >> 6;
    for (int e = wid; e < n_edges; e += nwave) {
        const float m = eval_[e] * xw[(size_t)ecol[e] * OUT_DIM + lane];
        atomicAdd(&out[(size_t)erow[e] * OUT_DIM + lane], m);
    }
}

__global__ __launch_bounds__(256) void relu_kernel(float4* __restrict__ p, int n4) {
    const int stride = gridDim.x * blockDim.x;
    for (int i = blockIdx.x * blockDim.x + threadIdx.x; i < n4; i += stride) {
        float4 v = p[i];
        v.x = fmaxf(v.x, 0.f); v.y = fmaxf(v.y, 0.f);
        v.z = fmaxf(v.z, 0.f); v.w = fmaxf(v.w, 0.f);
        p[i] = v;
    }
}

extern "C" void kernel_launch(void* const* d_in, const int* in_sizes, int n_in,
                              void* d_out, int out_size, void* d_ws, size_t ws_size,
                              hipStream_t stream) {
    const float* x     = (const float*)d_in[0];
    const int*   erow  = (const int*)d_in[1];
    const int*   ecol  = (const int*)d_in[2];
    const float* eval_ = (const float*)d_in[3];
    const float* W     = (const float*)d_in[4];
    const float* b     = (const float*)d_in[5];
    float*       out   = (float*)d_out;

    const int n_nodes = in_sizes[0] / IN_DIM;
    const int n_edges = in_sizes[1];

    // ---- workspace layout (256B aligned) ----
    auto align256 = [](size_t v) { return (v + 255) & ~(size_t)255; };
    size_t off_xw   = 0;
    size_t off_hist = align256(off_xw   + (size_t)n_nodes * OUT_DIM * 4);
    size_t off_off  = align256(off_hist + (size_t)n_nodes * 4);
    size_t off_bsum = align256(off_off  + (size_t)n_nodes * 4);
    size_t off_ecs  = align256(off_bsum + (size_t)2048 * 4);
    size_t need     = off_ecs + (size_t)n_edges * 8;

    float* xw = (float*)((char*)d_ws + off_xw);

    // 1) xw = x @ W + b
    gemm_xw_kernel<<<(n_nodes + 3) / 4, 256, 0, stream>>>(x, W, b, xw, n_nodes);

    if (need <= ws_size) {
        int*  hist = (int*)((char*)d_ws + off_hist);
        int*  off  = (int*)((char*)d_ws + off_off);
        int*  bsum = (int*)((char*)d_ws + off_bsum);
        int2* ecs  = (int2*)((char*)d_ws + off_ecs);

        const int nb = (n_nodes + SCAN_CHUNK - 1) / SCAN_CHUNK;   // <= 2048

        hipMemsetAsync(hist, 0, (size_t)n_nodes * 4, stream);
        hist_kernel<<<(n_edges + 255) / 256, 256, 0, stream>>>(erow, hist, n_edges);
        scan_block_kernel<<<nb, 256, 0, stream>>>(hist, off, bsum, n_nodes);
        scan_top_kernel<<<1, 256, 0, stream>>>(bsum, nb);
        reorder_kernel<<<(n_edges + 255) / 256, 256, 0, stream>>>(
            erow, ecol, eval_, off, bsum, ecs, n_edges);
        gather_relu_kernel<<<(n_nodes + 3) / 4, 256, 0, stream>>>(
            xw, ecs, off, bsum, out, n_nodes);
    } else {
        // fallback: atomic scatter
        hipMemsetAsync(d_out, 0, (size_t)out_size * sizeof(float), stream);
        edge_scatter_kernel<<<8192, 256, 0, stream>>>(xw, erow, ecol, eval_, out, n_edges);
        relu_kernel<<<2048, 256, 0, stream>>>((float4*)d_out, out_size / 4);
    }
}